// Round 13
// baseline (64.691 us; speedup 1.0000x reference)
//
#include <hip/hip_runtime.h>
#include <cstdint>

static constexpr int BATCH = 64;
static constexpr int NPB   = 512 * 512;   // elements per batch
static constexpr int NFB   = 2048;        // fine bins for the (subsampled) Otsu hist
static constexpr int PBLK  = 8;           // blocks per batch (512 total)
static constexpr int ELB   = NPB / PBLK;  // 32768 elements per block

// d_ws layout in 32-bit words (~570 KB):
static constexpr int W_MINK = 0;      // 512: per-block min key (atomicExch-published)
static constexpr int W_MAXK = 512;    // 512: per-block max key
static constexpr int W_T1   = 1024;   // 64 tickets, 32-word (128 B) stride
static constexpr int W_T2   = 3072;   // 64 tickets, 32-word stride
static constexpr int W_J    = 5120;   // 64 J-words, 32-word stride (sentinel 0xFFFFFFFF)
static constexpr int W_CNT  = 7168;   // nb[64], nt[64], ni[64]
static constexpr int W_BH   = 8192;   // 64 x 2048: per-batch subsample hist

__device__ __forceinline__ uint32_t fkey(float f) {   // monotone float->uint key
  uint32_t u = __float_as_uint(f);
  return u ^ ((u & 0x80000000u) ? 0xFFFFFFFFu : 0x80000000u);
}
__device__ __forceinline__ float funkey(uint32_t k) {
  uint32_t u = (k & 0x80000000u) ? (k ^ 0x80000000u) : ~k;
  return __uint_as_float(u);
}
__device__ __forceinline__ float sigmoidf(float v) {  // precise: pmin/pmax only
  if (v >= 0.0f) return 1.0f / (1.0f + expf(-v));
  float e = expf(v);
  return e / (1.0f + e);
}
__device__ __forceinline__ float fsig(float v) {      // fast: per-element binning only
  return __builtin_amdgcn_rcpf(1.0f + __expf(-v));
}
__device__ __forceinline__ uint32_t llc_load(const uint32_t* p) {  // served at LLC
  return __hip_atomic_load(p, __ATOMIC_RELAXED, __HIP_MEMORY_SCOPE_SYSTEM);
}

// Init: zero per-batch hists/tickets/counters/out; J words to sentinel.
__global__ __launch_bounds__(256) void k_init(uint32_t* __restrict__ ws,
                                              float* __restrict__ out) {
  const int j = blockIdx.x, t = threadIdx.x;
  uint32_t* bh = ws + W_BH + (size_t)j * NFB;
#pragma unroll
  for (int q = 0; q < 2; ++q)
    reinterpret_cast<uint4*>(bh)[t + q * 256] = uint4{0u, 0u, 0u, 0u};
  if (j == 0) {
    for (int i = W_T1 + t; i < W_CNT + 192; i += 256)
      ws[i] = (i >= W_J && i < W_CNT) ? 0xFFFFFFFFu : 0u;
    if (t == 0) out[0] = 0.0f;
  }
}

// Single data pass: codes-in-registers + subsampled hist -> leader Otsu -> LLC-spin
// on J -> register count -> per-batch counters -> last block writes IoU/64.
// LDS 8.3 KiB, ~75 VGPR -> >=4 blocks/CU capacity vs 2 resident needed (2x margin).
__global__ __launch_bounds__(256) void k_main(const float* __restrict__ x,
                                              const float* __restrict__ tg,
                                              uint32_t* __restrict__ ws,
                                              float* __restrict__ out) {
  __shared__ uint32_t h[NFB];            // 8 KiB: subsample hist, later Otsu scratch
  __shared__ float smn[4], smx[4];
  __shared__ unsigned long long sw[4];
  __shared__ uint32_t sJ;
  __shared__ int sFlag, sDeg;
  __shared__ float sPmin, sScale512, sBinw;
  const int t = threadIdx.x, g = blockIdx.x;
  const int b = g >> 3, blk = g & 7;
#pragma unroll
  for (int q = 0; q < 2; ++q)
    reinterpret_cast<uint4*>(h)[t + q * 256] = uint4{0u, 0u, 0u, 0u};
  __syncthreads();

  const size_t base = (size_t)b * NPB + (size_t)blk * ELB;
  const float4* px = reinterpret_cast<const float4*>(x + base);
  const float4* pt = reinterpret_cast<const float4*>(tg + base);

  // ---- phase 1: ONE stream of x+tg; 8-bit codes + tbits in registers;
  //      min/max; 1/4-subsampled 2048-bin LDS hist ----
  uint32_t codes[32];                    // 4 x 8-bit fixed-grid bins per word (static idx)
  uint32_t tmask[4] = {0u, 0u, 0u, 0u};  // 4 target bits per iter (nibbles)
  uint32_t nt_loc = 0;
  float mn = INFINITY, mx = -INFINITY;
#pragma unroll
  for (int i = 0; i < 32; ++i) {
    float4 v = px[i * 256 + t];
    float4 w = pt[i * 256 + t];
    mn = fminf(mn, fminf(fminf(v.x, v.y), fminf(v.z, v.w)));
    mx = fmaxf(mx, fmaxf(fmaxf(v.x, v.y), fmaxf(v.z, v.w)));
    const float f0 = fsig(v.x), f1 = fsig(v.y), f2 = fsig(v.z), f3 = fsig(v.w);
    int i0 = (int)(f0 * 256.0f); i0 = i0 > 255 ? 255 : i0;
    int i1 = (int)(f1 * 256.0f); i1 = i1 > 255 ? 255 : i1;
    int i2 = (int)(f2 * 256.0f); i2 = i2 > 255 ? 255 : i2;
    int i3 = (int)(f3 * 256.0f); i3 = i3 > 255 ? 255 : i3;
    codes[i] = (uint32_t)i0 | ((uint32_t)i1 << 8) | ((uint32_t)i2 << 16) | ((uint32_t)i3 << 24);
    const uint32_t b0 = w.x > 0.5f, b1 = w.y > 0.5f, b2 = w.z > 0.5f, b3 = w.w > 0.5f;
    nt_loc += b0 + b1 + b2 + b3;
    tmask[i >> 3] |= (b0 | (b1 << 1) | (b2 << 2) | (b3 << 3)) << ((i & 7) * 4);
    if ((i & 3) == 0) {                  // 1/4 subsample -> fine Otsu hist
#define PUT(f) { int s_ = (int)((f) * 2048.0f); s_ = s_ > 2047 ? 2047 : s_;        \
                 (void)__hip_atomic_fetch_add(&h[s_], 1u, __ATOMIC_RELAXED,        \
                                              __HIP_MEMORY_SCOPE_WORKGROUP); }
      PUT(f0) PUT(f1) PUT(f2) PUT(f3)
#undef PUT
    }
  }
  for (int off = 32; off; off >>= 1) {
    mn = fminf(mn, __shfl_down(mn, off));
    mx = fmaxf(mx, __shfl_down(mx, off));
  }
  if ((t & 63) == 0) { smn[t >> 6] = mn; smx[t >> 6] = mx; }
  __syncthreads();                       // LDS atomics + smn/smx done
  if (t == 0) {
    mn = fminf(fminf(smn[0], smn[1]), fminf(smn[2], smn[3]));
    mx = fmaxf(fmaxf(smx[0], smx[1]), fmaxf(smx[2], smx[3]));
    atomicExch(&ws[W_MINK + g], fkey(mn));   // publish at LLC
    atomicExch(&ws[W_MAXK + g], fkey(mx));
  }
  // publish subsample hist into the per-batch hist (device atomics at LLC)
#pragma unroll
  for (int q = 0; q < 8; ++q) {
    const int w_ = t + q * 256;
    const uint32_t c = h[w_];
    if (c) atomicAdd(&ws[W_BH + (size_t)b * NFB + w_], c);
  }
  __syncthreads();                       // every wave drains vmcnt -> publishes at LLC
  if (t == 0) {
    const uint32_t old = atomicAdd(&ws[W_T1 + b * 32], 1u);
    sFlag = (old == PBLK - 1);
  }
  __syncthreads();

  // ---- leader (last arriver of the 8): Otsu from per-batch hist -> publish J ----
  if (sFlag) {
    if (t == 0) sJ = 0xFFFFFFFFu;
    uint32_t mk = 0xFFFFFFFFu, xk = 0u;
    if (t < 8) {
      mk = llc_load(&ws[W_MINK + b * 8 + t]);
      xk = llc_load(&ws[W_MAXK + b * 8 + t]);
    }
    for (int off = 4; off; off >>= 1) {
      mk = min(mk, (uint32_t)__shfl_down((int)mk, off));
      xk = max(xk, (uint32_t)__shfl_down((int)xk, off));
    }
    if (t == 0) {
      const float pmin = sigmoidf(funkey(mk));
      const float pmax = sigmoidf(funkey(xk));
      const float span = pmax - pmin;
      sPmin = pmin;
      sDeg = !(span > 0.0f);
      sScale512 = (span > 0.0f) ? (512.0f / span) : 0.0f;
      sBinw = span * (1.0f / 256.0f);
    }
    uint32_t* h256 = h;                                  // [0..255]
    uint32_t* w1s  = h + 256;
    float*    s1s  = reinterpret_cast<float*>(h + 512);
    float*    vv   = reinterpret_cast<float*>(h + 768);
    int*      vi   = reinterpret_cast<int*>(h + 1024);
    h256[t] = 0u;
    __syncthreads();
    const float pmin = sPmin, scale = sScale512, binw = sBinw;
#pragma unroll
    for (int q = 0; q < 8; ++q) {        // batch fine hist -> 256-bin Otsu hist
      const int k = t + q * 256;
      const uint32_t val = llc_load(&ws[W_BH + (size_t)b * NFB + k]);
      if (val) {
        const float rep = ((float)k + 0.5f) * (1.0f / 2048.0f);
        int ci = (int)((rep - pmin) * scale);
        ci = ci < 0 ? 0 : (ci > 511 ? 511 : ci);
        atomicAdd(&h256[ci >> 1], val);
      }
    }
    __syncthreads();
    const uint32_t hk = h256[t];
    const float ck = pmin + ((float)t + 0.5f) * binw;    // centers[t]
    w1s[t] = hk;
    s1s[t] = (float)hk * ck;
    for (int off = 1; off < 256; off <<= 1) {            // Hillis-Steele scans
      __syncthreads();
      uint32_t wp = (t >= off) ? w1s[t - off] : 0u;
      float    sp = (t >= off) ? s1s[t - off] : 0.0f;
      __syncthreads();
      w1s[t] += wp; s1s[t] += sp;
    }
    __syncthreads();
    const uint32_t totW = w1s[255];
    const float totS = s1s[255];
    float vval = -INFINITY;
    if (t < 255 && w1s[t] > 0u && totW > w1s[t]) {
      const float w1f = (float)w1s[t];
      const float w2f = (float)(totW - w1s[t]);
      const float m1 = s1s[t] / w1f;
      const float m2 = (totS - s1s[t]) / w2f;
      const float d = m1 - m2;
      vval = (w1f * w2f) * (d * d);
    }
    vv[t] = vval; vi[t] = t;
    for (int s = 128; s; s >>= 1) {      // argmax, first-occurrence tie-break
      __syncthreads();
      if (t < s) {
        const float vb = vv[t + s]; const int ib = vi[t + s];
        if (vb > vv[t] || (vb == vv[t] && ib < vi[t])) { vv[t] = vb; vi[t] = ib; }
      }
    }
    __syncthreads();
    const int Jh = 2 * vi[0] + 1;        // halfbin boundary index
    {                                    // map to the 8-bit code grid: one k per thread
      const float rep = ((float)t + 0.5f) * (1.0f / 256.0f);
      int ci = (int)((rep - pmin) * scale);
      ci = ci < 0 ? 0 : (ci > 511 ? 511 : ci);
      if (ci >= Jh) atomicMin(&sJ, (uint32_t)t);
    }
    __syncthreads();
    if (t == 0) {
      const uint32_t Jp = (sDeg || sJ == 0xFFFFFFFFu) ? 0xFFFFu : sJ;
      atomicExch(&ws[W_J + b * 32], Jp);
    }
  }

  // ---- all blocks: wait for this batch's J (LLC poll, R7-proven) ----
  if (t == 0) {
    uint32_t jv;
    while ((jv = llc_load(&ws[W_J + b * 32])) == 0xFFFFFFFFu)
      __builtin_amdgcn_s_sleep(16);
    sJ = jv;
  }
  __syncthreads();
  const uint32_t J = sJ;

  // ---- count from register codes (no memory re-read) ----
  uint32_t nb = 0, ni = 0;
#pragma unroll
  for (int i = 0; i < 32; ++i) {
    const uint32_t c = codes[i];
    const uint32_t m = (tmask[i >> 3] >> ((i & 7) * 4)) & 0xFu;
#pragma unroll
    for (int e = 0; e < 4; ++e) {
      const uint32_t idx = (c >> (8 * e)) & 0xFFu;
      const uint32_t ge = idx >= J ? 1u : 0u;
      nb += ge;
      ni += ge & ((m >> e) & 1u);
    }
  }
  unsigned long long P = (unsigned long long)nb |
                         ((unsigned long long)nt_loc << 20) |
                         ((unsigned long long)ni << 40);
  for (int off = 32; off; off >>= 1) P += __shfl_down(P, off);
  if ((t & 63) == 0) sw[t >> 6] = P;
  __syncthreads();
  if (t == 0) {
    P = sw[0] + sw[1] + sw[2] + sw[3];
    atomicAdd(&ws[W_CNT + b],       (uint32_t)(P & 0xFFFFFu));
    atomicAdd(&ws[W_CNT + 64 + b],  (uint32_t)((P >> 20) & 0xFFFFFu));
    atomicAdd(&ws[W_CNT + 128 + b], (uint32_t)((P >> 40) & 0xFFFFFu));
    asm volatile("s_waitcnt vmcnt(0)" ::: "memory");   // counts at LLC BEFORE ticket
    const uint32_t old = atomicAdd(&ws[W_T2 + b * 32], 1u);
    if (old == PBLK - 1) {               // last block of this batch
      const float NB = (float)llc_load(&ws[W_CNT + b]);
      const float NT = (float)llc_load(&ws[W_CNT + 64 + b]);
      const float NI = (float)llc_load(&ws[W_CNT + 128 + b]);
      atomicAdd(out, ((NI + 1.0f) / ((NB + NT - NI) + 1.0f)) * (1.0f / 64.0f));
    }
  }
}

extern "C" void kernel_launch(void* const* d_in, const int* in_sizes, int n_in,
                              void* d_out, int out_size, void* d_ws, size_t ws_size,
                              hipStream_t stream) {
  const float* x  = (const float*)d_in[0];   // logits (64,1,512,512)
  const float* tg = (const float*)d_in[1];   // target (64,1,512,512)
  uint32_t* ws = (uint32_t*)d_ws;
  float* out = (float*)d_out;

  hipLaunchKernelGGL(k_init, dim3(BATCH),        dim3(256), 0, stream, ws, out);
  hipLaunchKernelGGL(k_main, dim3(BATCH * PBLK), dim3(256), 0, stream, x, tg, ws, out);
}

// Round 14
// 45.757 us; speedup vs baseline: 1.4138x; 1.4138x over previous
//
#include <hip/hip_runtime.h>
#include <cstdint>

static constexpr int BATCH = 64;
static constexpr int NPB   = 512 * 512;   // elements per batch
static constexpr int NFB   = 2048;        // fine fixed bins in sigmoid space [0,1]
static constexpr int PBLK  = 8;           // blocks per batch (512 total)
static constexpr int ELB   = NPB / PBLK;  // 32768 elements per block

// d_ws layout in 32-bit words (~4.1 MB):
static constexpr int W_BMIN = 0;      // 512 blocks x 4 waves = 2048 floats
static constexpr int W_BMAX = 2048;   // 2048 floats
static constexpr int W_T1   = 4096;   // 64 tickets, 32-word (128 B) stride
static constexpr int W_T2   = 6144;   // 64 tickets, 32-word stride
static constexpr int W_J    = 8192;   // 64 J words, 32-word stride (sentinel 0xFFFFFFFF)
static constexpr int W_CNT  = 10240;  // nb[64], nt[64], ni[64]
static constexpr int W_PART = 10496;  // 512 x 2048 u32 partial fine hists

__device__ __forceinline__ float sigmoidf(float v) {  // precise: pmin/pmax only
  if (v >= 0.0f) return 1.0f / (1.0f + expf(-v));
  float e = expf(v);
  return e / (1.0f + e);
}
__device__ __forceinline__ float fsig(float v) {      // fast: per-element binning only
  return __builtin_amdgcn_rcpf(1.0f + __expf(-v));
}
__device__ __forceinline__ uint32_t llc_load(const uint32_t* p) {   // served at LLC
  return __hip_atomic_load(p, __ATOMIC_RELAXED, __HIP_MEMORY_SCOPE_SYSTEM);
}
__device__ __forceinline__ float llc_loadf(const float* p) {
  return __hip_atomic_load(p, __ATOMIC_RELAXED, __HIP_MEMORY_SCOPE_SYSTEM);
}
__device__ __forceinline__ void llc_store(uint32_t* p, uint32_t v) {  // write-through
  __hip_atomic_store(p, v, __ATOMIC_RELAXED, __HIP_MEMORY_SCOPE_SYSTEM);
}
__device__ __forceinline__ void llc_storef(float* p, float v) {
  __hip_atomic_store(p, v, __ATOMIC_RELAXED, __HIP_MEMORY_SCOPE_SYSTEM);
}

// Init: tickets/J/counters/out. 25 blocks x 256 covers words [4096, 10432).
__global__ __launch_bounds__(256) void k_init(uint32_t* __restrict__ ws,
                                              float* __restrict__ out) {
  const int i = blockIdx.x * 256 + threadIdx.x;
  const int w = 4096 + i;
  if (w < W_CNT + 192) ws[w] = (w >= W_J && w < W_CNT) ? 0xFFFFFFFFu : 0u;
  if (i == 0) out[0] = 0.0f;
}

// Fused single-stream kernel. 512 blocks x 256 thr; ~46 KiB LDS -> 3 blocks/CU
// -> 768 slots >= 512: ALL blocks co-resident (spin is deadlock-free by capacity).
__global__ __launch_bounds__(256, 3) void k_main(const float* __restrict__ x,
                                                 const float* __restrict__ tg,
                                                 uint32_t* __restrict__ ws,
                                                 float* __restrict__ out) {
  __shared__ uint32_t c8[ELB / 4];       // 32 KiB: 8-bit codes, 4 packed per u32
  __shared__ uint32_t hist[NFB];         // 8 KiB: subsample hist; leader reuses as tot
  __shared__ uint32_t scanA[256];        // w1 scan
  __shared__ float    scanB[256];        // s1 scan
  __shared__ float    scanC[256];        // argmax values
  __shared__ int      scanD[256];        // argmax indices
  __shared__ uint32_t h256[256];         // 256-bin Otsu hist
  __shared__ unsigned long long sw[4];
  __shared__ uint32_t sJ;
  __shared__ int sFlag;
  __shared__ float sPmin, sScale, sBinw;
  const int t = threadIdx.x, g = blockIdx.x;
  const int b = g >> 3, blk = g & 7;
  float* wsf = reinterpret_cast<float*>(ws);

#pragma unroll
  for (int q = 0; q < 2; ++q)
    reinterpret_cast<uint4*>(hist)[t + q * 256] = uint4{0u, 0u, 0u, 0u};
  __syncthreads();

  const size_t base = (size_t)b * NPB + (size_t)blk * ELB;
  const float4* px = reinterpret_cast<const float4*>(x + base);
  const float4* pt = reinterpret_cast<const float4*>(tg + base);

  // ---- phase 1: ONE stream. codes->LDS, tmask->VGPR, min/max, 1/4-sub hist ----
  uint32_t tmask[4];
  float mn = INFINITY, mx = -INFINITY;
#pragma unroll
  for (int o = 0; o < 4; ++o) {
    uint32_t tm = 0u;
#pragma unroll
    for (int ii = 0; ii < 8; ++ii) {
      const int i = o * 8 + ii;
      float4 v = px[i * 256 + t];
      float4 w = pt[i * 256 + t];
      mn = fminf(mn, fminf(fminf(v.x, v.y), fminf(v.z, v.w)));
      mx = fmaxf(mx, fmaxf(fmaxf(v.x, v.y), fmaxf(v.z, v.w)));
      const float f0 = fsig(v.x), f1 = fsig(v.y), f2 = fsig(v.z), f3 = fsig(v.w);
      int i0 = (int)(f0 * 256.0f); i0 = i0 > 255 ? 255 : i0;
      int i1 = (int)(f1 * 256.0f); i1 = i1 > 255 ? 255 : i1;
      int i2 = (int)(f2 * 256.0f); i2 = i2 > 255 ? 255 : i2;
      int i3 = (int)(f3 * 256.0f); i3 = i3 > 255 ? 255 : i3;
      c8[i * 256 + t] = (uint32_t)i0 | ((uint32_t)i1 << 8) |
                        ((uint32_t)i2 << 16) | ((uint32_t)i3 << 24);
      const uint32_t b0 = w.x > 0.5f, b1 = w.y > 0.5f, b2 = w.z > 0.5f, b3 = w.w > 0.5f;
      tm |= (b0 | (b1 << 1) | (b2 << 2) | (b3 << 3)) << (ii * 4);
      if ((ii & 3) == 0) {               // 1/4 subsample -> 2048-bin Otsu hist
#define PUT(f) { int s_ = (int)((f) * 2048.0f); s_ = s_ > 2047 ? 2047 : s_;      \
                 (void)__hip_atomic_fetch_add(&hist[s_], 1u, __ATOMIC_RELAXED,   \
                                              __HIP_MEMORY_SCOPE_WORKGROUP); }
        PUT(f0) PUT(f1) PUT(f2) PUT(f3)
#undef PUT
      }
    }
    tmask[o] = tm;
  }
  for (int off = 32; off; off >>= 1) {
    mn = fminf(mn, __shfl_down(mn, off));
    mx = fmaxf(mx, __shfl_down(mx, off));
  }
  if ((t & 63) == 0) {                   // per-wave min/max -> LLC (write-through)
    llc_storef(&wsf[W_BMIN + g * 4 + (t >> 6)], mn);
    llc_storef(&wsf[W_BMAX + g * 4 + (t >> 6)], mx);
  }
  __syncthreads();                       // hist LDS atomics complete
  // flush partial hist to this block's slot via system-scope stores (at LLC)
  uint32_t* gp = ws + W_PART + (size_t)g * NFB;
#pragma unroll
  for (int q = 0; q < 8; ++q)
    llc_store(&gp[t + q * 256], hist[t + q * 256]);
  __syncthreads();                       // every wave drains vmcnt entering barrier
  if (t == 0) {
    asm volatile("s_waitcnt vmcnt(0)" ::: "memory");
    const uint32_t old = atomicAdd(&ws[W_T1 + b * 32], 1u);
    sFlag = (old == PBLK - 1);
  }
  __syncthreads();

  // ---- leader (last arriver of the batch): Otsu -> K8 -> publish J ----
  if (sFlag) {
#pragma unroll
    for (int q = 0; q < 8; ++q) {        // merge 8 partials (LLC loads) into 'tot'
      const int k = t + q * 256;
      uint32_t s = 0;
#pragma unroll
      for (int p = 0; p < PBLK; ++p)
        s += llc_load(&ws[W_PART + (size_t)(b * PBLK + p) * NFB + k]);
      hist[k] = s;
    }
    h256[t] = 0u;
    float mnv = INFINITY, mxv = -INFINITY;
    if (t < 32) {
      mnv = llc_loadf(&wsf[W_BMIN + b * 32 + t]);
      mxv = llc_loadf(&wsf[W_BMAX + b * 32 + t]);
    }
    for (int off = 16; off; off >>= 1) {
      mnv = fminf(mnv, __shfl_down(mnv, off));
      mxv = fmaxf(mxv, __shfl_down(mxv, off));
    }
    if (t == 0) {
      const float pmin = sigmoidf(mnv);
      const float pmax = sigmoidf(mxv);
      const float span = pmax - pmin;
      sPmin = pmin;
      sScale = (span > 0.0f) ? (512.0f / span) : -1.0f;   // negative = degenerate
      sBinw = span * (1.0f / 256.0f);
    }
    __syncthreads();
    const float pmin = sPmin, scale = sScale, binw = sBinw;
    if (scale < 0.0f) {
      if (t == 0) atomicExch(&ws[W_J + b * 32], 256u);    // count none (matches ref)
    } else {
#pragma unroll
      for (int q = 0; q < 8; ++q) {      // fine -> 256-bin via midpoint halfbin map
        const int k = t + q * 256;
        const uint32_t c = hist[k];
        if (c) {
          const float rep = ((float)k + 0.5f) * (1.0f / 2048.0f);
          int ci = (int)((rep - pmin) * scale);
          ci = ci < 0 ? 0 : (ci > 511 ? 511 : ci);
          atomicAdd(&h256[ci >> 1], c);
        }
      }
      __syncthreads();
      const uint32_t hk = h256[t];
      const float ck = pmin + ((float)t + 0.5f) * binw;   // centers[t]
      scanA[t] = hk;
      scanB[t] = (float)hk * ck;
      for (int off = 1; off < 256; off <<= 1) {           // Hillis-Steele scans
        __syncthreads();
        uint32_t wp = (t >= off) ? scanA[t - off] : 0u;
        float    sp = (t >= off) ? scanB[t - off] : 0.0f;
        __syncthreads();
        scanA[t] += wp; scanB[t] += sp;
      }
      __syncthreads();
      const uint32_t totW = scanA[255];
      const float totS = scanB[255];
      float vv = -INFINITY;
      if (t < 255 && scanA[t] > 0u && totW > scanA[t]) {
        const float w1f = (float)scanA[t];
        const float w2f = (float)(totW - scanA[t]);
        const float m1 = scanB[t] / w1f;
        const float m2 = (totS - scanB[t]) / w2f;
        const float d = m1 - m2;
        vv = (w1f * w2f) * (d * d);
      }
      scanC[t] = vv; scanD[t] = t;
      for (int s = 128; s; s >>= 1) {    // argmax, first-occurrence tie-break
        __syncthreads();
        if (t < s) {
          const float vb = scanC[t + s]; const int ib = scanD[t + s];
          if (vb > scanC[t] || (vb == scanC[t] && ib < scanD[t])) {
            scanC[t] = vb; scanD[t] = ib;
          }
        }
      }
      __syncthreads();
      const int Jh = 2 * scanD[0] + 1;   // halfbin boundary index
      if (t == 0) sJ = 256u;
      __syncthreads();
      {                                  // min code-grid k whose midpoint maps >= Jh
        const float rep = ((float)t + 0.5f) * (1.0f / 256.0f);
        int ci = (int)((rep - pmin) * scale);
        ci = ci < 0 ? 0 : (ci > 511 ? 511 : ci);
        if (ci >= Jh) atomicMin(&sJ, (uint32_t)t);
      }
      __syncthreads();
      if (t == 0) atomicExch(&ws[W_J + b * 32], sJ);
    }
  }

  // ---- all blocks: poll this batch's J at the LLC ----
  if (t == 0) {
    uint32_t jv;
    while ((jv = llc_load(&ws[W_J + b * 32])) == 0xFFFFFFFFu)
      __builtin_amdgcn_s_sleep(16);
    sJ = jv;
  }
  __syncthreads();
  const uint32_t K8 = sJ;

  // ---- count from LDS codes + register tmask (no memory re-read) ----
  uint32_t nb = 0, ni = 0, nt = 0;
#pragma unroll
  for (int o = 0; o < 4; ++o) {
    const uint32_t tm = tmask[o];
    nt += __popc(tm);
#pragma unroll
    for (int ii = 0; ii < 8; ++ii) {
      const int i = o * 8 + ii;
      const uint32_t cw = c8[i * 256 + t];
      const uint32_t m = (tm >> (ii * 4)) & 0xFu;
#pragma unroll
      for (int e = 0; e < 4; ++e) {
        const uint32_t ge = ((cw >> (8 * e)) & 0xFFu) >= K8 ? 1u : 0u;
        nb += ge;
        ni += ge & ((m >> e) & 1u);
      }
    }
  }
  unsigned long long P = (unsigned long long)nb |
                         ((unsigned long long)nt << 20) |
                         ((unsigned long long)ni << 40);
  for (int off = 32; off; off >>= 1) P += __shfl_down(P, off);
  if ((t & 63) == 0) sw[t >> 6] = P;
  __syncthreads();
  if (t == 0) {
    P = sw[0] + sw[1] + sw[2] + sw[3];
    atomicAdd(&ws[W_CNT + b],       (uint32_t)(P & 0xFFFFFu));
    atomicAdd(&ws[W_CNT + 64 + b],  (uint32_t)((P >> 20) & 0xFFFFFu));
    atomicAdd(&ws[W_CNT + 128 + b], (uint32_t)((P >> 40) & 0xFFFFFu));
    asm volatile("s_waitcnt vmcnt(0)" ::: "memory");   // counts at LLC BEFORE ticket
    const uint32_t old = atomicAdd(&ws[W_T2 + b * 32], 1u);
    if (old == PBLK - 1) {               // last block of this batch -> IoU
      const float NB = (float)llc_load(&ws[W_CNT + b]);
      const float NT = (float)llc_load(&ws[W_CNT + 64 + b]);
      const float NI = (float)llc_load(&ws[W_CNT + 128 + b]);
      atomicAdd(out, ((NI + 1.0f) / ((NB + NT - NI) + 1.0f)) * (1.0f / 64.0f));
    }
  }
}

extern "C" void kernel_launch(void* const* d_in, const int* in_sizes, int n_in,
                              void* d_out, int out_size, void* d_ws, size_t ws_size,
                              hipStream_t stream) {
  const float* x  = (const float*)d_in[0];   // logits (64,1,512,512)
  const float* tg = (const float*)d_in[1];   // target (64,1,512,512)
  uint32_t* ws = (uint32_t*)d_ws;
  float* out = (float*)d_out;

  hipLaunchKernelGGL(k_init, dim3(25),           dim3(256), 0, stream, ws, out);
  hipLaunchKernelGGL(k_main, dim3(BATCH * PBLK), dim3(256), 0, stream, x, tg, ws, out);
}